// Round 6
// baseline (288.269 us; speedup 1.0000x reference)
//
#include <hip/hip_runtime.h>

// FNO3d forward, MI355X. Round 12 (on R11 base, 282.5us):
//  - invN3 folded into Ps write; Hermitian x2 factor folded into Qs write
//    (kz>=1): removes 2 pk-muls per (o,p) from k_ptA/k_ptout main loops.
//  - Qs phase: one fused loop per thread covering o and o+4 (same dy,kz) --
//    shared twiddle loads + index arithmetic.
//  - k_fH: kz-paired. One float4 load per dy covers kz pair; shared twiddles;
//    float4 store. Halves loads, ~40% fewer instructions. grid 256.
//  - R11 packed-fp32 main loops kept; k_fDmix/k_liftA unchanged.
//
// Layouts:
//   x  : float [B=8][C=8][64][64][64]          (67,108,864 B)
//   A  : float2[8][8][dx=64][dy=64][kz=4]      ( 8,388,608 B)
//   Bh : float2[8][8][dx=64][ky=8][kz=4]       ( 1,048,576 B)
//   O  : float2[8][8][kx=8][ky=8][kz=4]        (   131,072 B)

#define TWO_PI_OVER_64 0.09817477042468103

typedef float v2f __attribute__((ext_vector_type(2)));

__device__ __forceinline__ float gelu_fast(float x) {
    float x2 = x * x;
    float p  = x * (1.0f + 0.044715f * x2);
    float e  = __builtin_amdgcn_exp2f(-2.3022083f * p);
    return x * __builtin_amdgcn_rcpf(1.0f + e);
}

__device__ __forceinline__ v2f gelu2(v2f x) {
    v2f x2 = x * x;
    v2f p  = x * (1.0f + 0.044715f * x2);
    v2f r;
    r.x = __builtin_amdgcn_rcpf(1.0f + __builtin_amdgcn_exp2f(-2.3022083f * p.x));
    r.y = __builtin_amdgcn_rcpf(1.0f + __builtin_amdgcn_exp2f(-2.3022083f * p.y));
    return x * r;
}

#define BUILD_TW() \
    __shared__ float twc[64], tws[64]; \
    if (threadIdx.x < 64) { \
        double a_ = TWO_PI_OVER_64 * (double)threadIdx.x; \
        twc[threadIdx.x] = (float)cos(a_); tws[threadIdx.x] = (float)sin(a_); \
    }

// Twiddle pair registers for the W-axis (w = wq*4 + {0..3}), packed by j-pair.
#define LOAD_WTW() \
    v2f c1p[2], s1p[2], c2p[2], s2p[2], c3p[2], s3p[2]; \
    _Pragma("unroll") \
    for (int p = 0; p < 2; ++p) { \
        int wa = wq * 4 + 2 * p, wb = wa + 1; \
        c1p[p] = (v2f){twc[wa], twc[wb]}; \
        s1p[p] = (v2f){tws[wa], tws[wb]}; \
        c2p[p] = (v2f){twc[(2 * wa) & 63], twc[(2 * wb) & 63]}; \
        s2p[p] = (v2f){tws[(2 * wa) & 63], tws[(2 * wb) & 63]}; \
        c3p[p] = (v2f){twc[(3 * wa) & 63], twc[(3 * wb) & 63]}; \
        s3p[p] = (v2f){tws[(3 * wa) & 63], tws[(3 * wb) & 63]}; \
    }

// DPP row_ror rotation-add: after steps 1,2,4,8 every lane of each 16-lane
// row holds the row sum. VALU-only (no ds_bpermute / LDS pipe).
#define ROR_STEP(x, CTRL) \
    x += __int_as_float(__builtin_amdgcn_update_dpp( \
            0, __float_as_int(x), CTRL, 0xF, 0xF, true))

__device__ __forceinline__ float red16_ror(float x) {
    ROR_STEP(x, 0x121);   // row_ror:1
    ROR_STEP(x, 0x122);   // row_ror:2
    ROR_STEP(x, 0x124);   // row_ror:4
    ROR_STEP(x, 0x128);   // row_ror:8
    return x;
}

// A-tail: partial W-DFT over this lane's 4 w-points (as 2 packed pairs),
// DPP reduce across the 16 wq-lanes, predicated float4 store.
__device__ __forceinline__ void a_tail_store(
    const v2f v[2], const v2f c1[2], const v2f s1[2],
    const v2f c2[2], const v2f s2[2], const v2f c3[2], const v2f s3[2],
    int wq, float2* __restrict__ Arow)
{
    v2f d;
    d = v[0] + v[1];               float p0  = d.x + d.y;
    d = v[0]*c1[0] + v[1]*c1[1];   float ar1 = d.x + d.y;
    d = v[0]*s1[0] + v[1]*s1[1];   float ai1 = -(d.x + d.y);
    d = v[0]*c2[0] + v[1]*c2[1];   float ar2 = d.x + d.y;
    d = v[0]*s2[0] + v[1]*s2[1];   float ai2 = -(d.x + d.y);
    d = v[0]*c3[0] + v[1]*c3[1];   float ar3 = d.x + d.y;
    d = v[0]*s3[0] + v[1]*s3[1];   float ai3 = -(d.x + d.y);
    p0  = red16_ror(p0);
    ar1 = red16_ror(ar1);  ai1 = red16_ror(ai1);
    ar2 = red16_ror(ar2);  ai2 = red16_ror(ai2);
    ar3 = red16_ror(ar3);  ai3 = red16_ror(ai3);
    if (wq < 2) {
        float4 av;
        av.x = (wq == 0) ? p0   : ar2;
        av.y = (wq == 0) ? 0.f  : ai2;
        av.z = (wq == 0) ? ar1  : ar3;
        av.w = (wq == 0) ? ai1  : ai3;
        *((float4*)Arow + wq) = av;
    }
}

// ---------------------------------------------------------------------------
// Lift (3->8 ch) + forward W-DFT (DPP tail), packed fp32.
// grid 2048 = b(8)*dx(64)*dyq(4); block 256 (dyl = t>>4, wq = t&15).
// ---------------------------------------------------------------------------
__global__ __launch_bounds__(256) void k_liftA(
    const float* __restrict__ u, const float* __restrict__ fc0w,
    const float* __restrict__ fc0b, float* __restrict__ x,
    float2* __restrict__ A)
{
    BUILD_TW();
    const int t = threadIdx.x, bid = blockIdx.x;
    const int b = bid >> 8, dx = (bid >> 2) & 63, dy0 = (bid & 3) * 16;
    const int dyl = t >> 4, wq = t & 15;
    const size_t sp = (size_t)dx * 4096 + (size_t)(dy0 + dyl) * 64 + wq * 4;
    v2f uin[3][2];
    #pragma unroll
    for (int c = 0; c < 3; ++c) {
        float4 v = *(const float4*)&u[(size_t)(b * 3 + c) * 262144 + sp];
        uin[c][0] = (v2f){v.x, v.y};
        uin[c][1] = (v2f){v.z, v.w};
    }
    __syncthreads();
    LOAD_WTW();
    #pragma unroll
    for (int o = 0; o < 8; ++o) {
        float w0 = fc0w[o * 3 + 0], w1 = fc0w[o * 3 + 1], w2 = fc0w[o * 3 + 2];
        float bb = fc0b[o];
        v2f vp[2];
        #pragma unroll
        for (int p = 0; p < 2; ++p)
            vp[p] = bb + uin[0][p] * w0 + uin[1][p] * w1 + uin[2][p] * w2;
        *(float4*)&x[(size_t)(b * 8 + o) * 262144 + sp] =
            make_float4(vp[0].x, vp[0].y, vp[1].x, vp[1].y);
        a_tail_store(vp, c1p, s1p, c2p, s2p, c3p, s3p, wq,
                     A + ((size_t)(b * 8 + o) * 4096 + dx * 64 + dy0 + dyl) * 4);
    }
}

// ---------------------------------------------------------------------------
// H-axis DFT, kz-paired: A[b,c,dx,dy,kz] -> Bh[b,c,dx,ky,kz].
// grid 256, block 256. Each thread: one float4 load per dy covers a kz pair,
// shared twiddles, one float4 store.
// ---------------------------------------------------------------------------
__global__ __launch_bounds__(256) void k_fH(const float2* __restrict__ A,
                                            float2* __restrict__ Bh)
{
    BUILD_TW();
    __syncthreads();
    const int g = blockIdx.x * 256 + threadIdx.x;   // 65536 total
    const int triple = g >> 4, idx = g & 15;
    const int ky = idx >> 1, kz2 = (idx & 1) * 2;
    const int b = triple >> 9, c = (triple >> 6) & 7, dx = triple & 63;
    const int kyv = ky < 4 ? ky : ky + 56;
    const float2* Ap = A + (size_t)(b * 8 + c) * 16384 + dx * 256 + kz2;
    float re0 = 0.f, im0 = 0.f, re1 = 0.f, im1 = 0.f;
    int ti = 0;
    #pragma unroll 8
    for (int dy = 0; dy < 64; ++dy) {
        float4 a = *(const float4*)&Ap[dy * 4];
        float cc = twc[ti], ss = tws[ti];
        re0 += a.x * cc + a.y * ss;   // * e^{-i phi}
        im0 += a.y * cc - a.x * ss;
        re1 += a.z * cc + a.w * ss;
        im1 += a.w * cc - a.z * ss;
        ti = (ti + kyv) & 63;
    }
    *(float4*)&Bh[(size_t)(b * 8 + c) * 2048 + dx * 32 + ky * 4 + kz2] =
        make_float4(re0, im0, re1, im1);
}

// ---------------------------------------------------------------------------
// D-axis DFT (into LDS) + spectral mix. grid 64, block 256. (R7)
// ---------------------------------------------------------------------------
__global__ __launch_bounds__(256) void k_fDmix(
    const float2* __restrict__ Bh,
    const float2* __restrict__ w1, const float2* __restrict__ w2,
    const float2* __restrict__ w3, const float2* __restrict__ w4,
    float2* __restrict__ O)
{
    BUILD_TW();
    __shared__ float2 Cs[256];   // [c][ky][kz] = c*32 + ky*4 + kz
    const int t = threadIdx.x, bid = blockIdx.x;
    const int b = bid >> 3, kx = bid & 7;
    const int kxv = kx < 4 ? kx : kx + 56;
    __syncthreads();
    {
        int kz = t & 3, ky = (t >> 2) & 7, c = t >> 5;
        const float2* Bp = Bh + (size_t)(b * 8 + c) * 2048 + ky * 4 + kz;
        float re = 0.f, im = 0.f;
        int ti = 0;
        #pragma unroll 8
        for (int dx = 0; dx < 64; ++dx) {
            float2 v = Bp[dx * 32];
            float cc = twc[ti], ss = tws[ti];
            re += v.x * cc + v.y * ss;
            im += v.y * cc - v.x * ss;
            ti = (ti + kxv) & 63;
        }
        Cs[t] = make_float2(re, im);
    }
    __syncthreads();
    {
        int kz = t & 3, ky = (t >> 2) & 7, o = t >> 5;
        const float2* wsel = (kx < 4) ? ((ky < 4) ? w1 : w3) : ((ky < 4) ? w2 : w4);
        int kxw = kx & 3, kyw = ky & 3;
        float re = 0.f, im = 0.f;
        #pragma unroll
        for (int i = 0; i < 8; ++i) {
            float2 cv = Cs[i * 32 + ky * 4 + kz];
            float2 wv = wsel[(((size_t)(i * 8 + o) * 4 + kxw) * 4 + kyw) * 4 + kz];
            re += cv.x * wv.x - cv.y * wv.y;
            im += cv.x * wv.y + cv.y * wv.x;
        }
        O[(((size_t)(b * 8 + o) * 8 + kx) * 8 + ky) * 4 + kz] = make_float2(re, im);
    }
}

// ---------------------------------------------------------------------------
// Inverse D/H DFT in LDS + irfftW + conv + gelu + x in place + next-layer A.
// Packed fp32; invN3 folded into Ps, x2 factor into Qs. grid 2048; block 256.
// ---------------------------------------------------------------------------
__global__ __launch_bounds__(256, 4) void k_ptA(
    float* __restrict__ x, const float2* __restrict__ O,
    const float* __restrict__ cw, const float* __restrict__ cb,
    float2* __restrict__ A)
{
    BUILD_TW();
    __shared__ float2 Ps[256];          // [o][ky][kz]
    __shared__ float2 Qs[8 * 16 * 4];   // [o][dyl][kz]
    const int t = threadIdx.x, bid = blockIdx.x;
    const int b = bid >> 8, dx = (bid >> 2) & 63, dy0 = (bid & 3) * 16;
    const int dyl = t >> 4, wq = t & 15;
    const size_t sp = (size_t)dx * 4096 + (size_t)(dy0 + dyl) * 64 + wq * 4;
    const float invN3 = 1.0f / 262144.0f;
    // ---- prefetch: all global loads issued before any barrier ----
    float4 xv[8];
    #pragma unroll
    for (int c = 0; c < 8; ++c)
        xv[c] = *(const float4*)&x[(size_t)(b * 8 + c) * 262144 + sp];
    const int pkz = t & 3, pky = (t >> 2) & 7, po = t >> 5;
    float2 ov[8];
    #pragma unroll
    for (int kxi = 0; kxi < 8; ++kxi)
        ov[kxi] = O[(((size_t)(b * 8 + po) * 8 + kxi) * 8 + pky) * 4 + pkz];
    __syncthreads();
    {   // Ps (pre-scaled by invN3)
        float re = 0.f, im = 0.f;
        #pragma unroll
        for (int kxi = 0; kxi < 8; ++kxi) {
            int kxv = kxi < 4 ? kxi : kxi + 56;
            int ti = (kxv * dx) & 63;
            float cc = twc[ti], ss = tws[ti];
            re += ov[kxi].x * cc - ov[kxi].y * ss;   // * e^{+i phi}
            im += ov[kxi].y * cc + ov[kxi].x * ss;
        }
        Ps[t] = make_float2(re * invN3, im * invN3);
    }
    __syncthreads();
    {   // Qs: o and o+4 share twiddles; Hermitian x2 folded in (kz>=1)
        const int kz = t & 3, qdyl = (t >> 2) & 15, o0 = t >> 6;
        const int dy = dy0 + qdyl;
        float re0 = 0.f, im0 = 0.f, re1 = 0.f, im1 = 0.f;
        #pragma unroll
        for (int kyi = 0; kyi < 8; ++kyi) {
            int kyv = kyi < 4 ? kyi : kyi + 56;
            int ti = (kyv * dy) & 63;
            float cc = twc[ti], ss = tws[ti];
            float2 va = Ps[(o0 * 8 + kyi) * 4 + kz];
            float2 vb = Ps[((o0 + 4) * 8 + kyi) * 4 + kz];
            re0 += va.x * cc - va.y * ss;
            im0 += va.y * cc + va.x * ss;
            re1 += vb.x * cc - vb.y * ss;
            im1 += vb.y * cc + vb.x * ss;
        }
        const float sc = kz ? 2.f : 1.f;
        Qs[(o0 * 16 + qdyl) * 4 + kz] = make_float2(re0 * sc, im0 * sc);
        Qs[((o0 + 4) * 16 + qdyl) * 4 + kz] = make_float2(re1 * sc, im1 * sc);
    }
    __syncthreads();
    LOAD_WTW();
    #pragma unroll
    for (int o = 0; o < 8; ++o) {
        float4 qa = *(const float4*)&Qs[(o * 16 + dyl) * 4];      // q0,q1
        float4 qb = *(const float4*)&Qs[(o * 16 + dyl) * 4 + 2];  // q2,q3
        const float cbo = cb[o];
        v2f outp[2];
        #pragma unroll
        for (int p = 0; p < 2; ++p) {
            v2f x1 = qa.x + (qa.z * c1p[p] - qa.w * s1p[p]
                           + qb.x * c2p[p] - qb.y * s2p[p]
                           + qb.z * c3p[p] - qb.w * s3p[p]);
            v2f x2 = (v2f){cbo, cbo};
            #pragma unroll
            for (int c = 0; c < 8; ++c) {
                const v2f* xp = (const v2f*)&xv[c];
                x2 += cw[o * 8 + c] * xp[p];
            }
            outp[p] = gelu2(x1 + x2);
        }
        *(float4*)&x[(size_t)(b * 8 + o) * 262144 + sp] =
            make_float4(outp[0].x, outp[0].y, outp[1].x, outp[1].y);
        a_tail_store(outp, c1p, s1p, c2p, s2p, c3p, s3p, wq,
                     A + ((size_t)(b * 8 + o) * 4096 + dx * 64 + dy0 + dyl) * 4);
    }
}

// ---------------------------------------------------------------------------
// Layer 3: inverse DFT + conv (no gelu) -> fc1+gelu+fc2, + hard core u*nu.
// Packed fp32; invN3/x2 folded as in k_ptA. grid 2048; block 256.
// ---------------------------------------------------------------------------
__global__ __launch_bounds__(256, 4) void k_ptout(
    const float* __restrict__ x, const float2* __restrict__ O,
    const float* __restrict__ cw, const float* __restrict__ cb,
    const float* __restrict__ u, const float* __restrict__ nu,
    const float* __restrict__ fc1w, const float* __restrict__ fc1b,
    const float* __restrict__ fc2w, const float* __restrict__ fc2b,
    float* __restrict__ out)
{
    BUILD_TW();
    __shared__ float2 Ps[256];
    __shared__ float2 Qs[8 * 16 * 4];
    const int t = threadIdx.x, bid = blockIdx.x;
    const int b = bid >> 8, dx = (bid >> 2) & 63, dy0 = (bid & 3) * 16;
    const int dyl = t >> 4, wq = t & 15;
    const size_t sp = (size_t)dx * 4096 + (size_t)(dy0 + dyl) * 64 + wq * 4;
    const float invN3 = 1.0f / 262144.0f;
    float4 xv[8];
    #pragma unroll
    for (int c = 0; c < 8; ++c)
        xv[c] = *(const float4*)&x[(size_t)(b * 8 + c) * 262144 + sp];
    float4 uv[3];
    #pragma unroll
    for (int c = 0; c < 3; ++c)
        uv[c] = *(const float4*)&u[(size_t)(b * 3 + c) * 262144 + sp];
    const int pkz = t & 3, pky = (t >> 2) & 7, po = t >> 5;
    float2 ovv[8];
    #pragma unroll
    for (int kxi = 0; kxi < 8; ++kxi)
        ovv[kxi] = O[(((size_t)(b * 8 + po) * 8 + kxi) * 8 + pky) * 4 + pkz];
    __syncthreads();
    {
        float re = 0.f, im = 0.f;
        #pragma unroll
        for (int kxi = 0; kxi < 8; ++kxi) {
            int kxv = kxi < 4 ? kxi : kxi + 56;
            int ti = (kxv * dx) & 63;
            float cc = twc[ti], ss = tws[ti];
            re += ovv[kxi].x * cc - ovv[kxi].y * ss;
            im += ovv[kxi].y * cc + ovv[kxi].x * ss;
        }
        Ps[t] = make_float2(re * invN3, im * invN3);
    }
    __syncthreads();
    {
        const int kz = t & 3, qdyl = (t >> 2) & 15, o0 = t >> 6;
        const int dy = dy0 + qdyl;
        float re0 = 0.f, im0 = 0.f, re1 = 0.f, im1 = 0.f;
        #pragma unroll
        for (int kyi = 0; kyi < 8; ++kyi) {
            int kyv = kyi < 4 ? kyi : kyi + 56;
            int ti = (kyv * dy) & 63;
            float cc = twc[ti], ss = tws[ti];
            float2 va = Ps[(o0 * 8 + kyi) * 4 + kz];
            float2 vb = Ps[((o0 + 4) * 8 + kyi) * 4 + kz];
            re0 += va.x * cc - va.y * ss;
            im0 += va.y * cc + va.x * ss;
            re1 += vb.x * cc - vb.y * ss;
            im1 += vb.y * cc + vb.x * ss;
        }
        const float sc = kz ? 2.f : 1.f;
        Qs[(o0 * 16 + qdyl) * 4 + kz] = make_float2(re0 * sc, im0 * sc);
        Qs[((o0 + 4) * 16 + qdyl) * 4 + kz] = make_float2(re1 * sc, im1 * sc);
    }
    __syncthreads();
    LOAD_WTW();
    v2f vvp[8][2];   // layer-3 activations (no gelu), packed j-pairs
    #pragma unroll
    for (int o = 0; o < 8; ++o) {
        float4 qa = *(const float4*)&Qs[(o * 16 + dyl) * 4];
        float4 qb = *(const float4*)&Qs[(o * 16 + dyl) * 4 + 2];
        const float cbo = cb[o];
        #pragma unroll
        for (int p = 0; p < 2; ++p) {
            v2f x1 = qa.x + (qa.z * c1p[p] - qa.w * s1p[p]
                           + qb.x * c2p[p] - qb.y * s2p[p]
                           + qb.z * c3p[p] - qb.w * s3p[p]);
            v2f x2 = (v2f){cbo, cbo};
            #pragma unroll
            for (int c = 0; c < 8; ++c) {
                const v2f* xp = (const v2f*)&xv[c];
                x2 += cw[o * 8 + c] * xp[p];
            }
            vvp[o][p] = x1 + x2;
        }
    }
    v2f so2[6][2];
    #pragma unroll
    for (int c6 = 0; c6 < 6; ++c6) {
        float bb = fc2b[c6];
        so2[c6][0] = (v2f){bb, bb};
        so2[c6][1] = (v2f){bb, bb};
    }
    #pragma unroll 4
    for (int h = 0; h < 32; ++h) {
        float wr[8];
        #pragma unroll
        for (int c = 0; c < 8; ++c) wr[c] = fc1w[h * 8 + c];   // uniform -> SGPR
        const float hb = fc1b[h];
        float w2r[6];
        #pragma unroll
        for (int c6 = 0; c6 < 6; ++c6) w2r[c6] = fc2w[c6 * 32 + h];
        #pragma unroll
        for (int p = 0; p < 2; ++p) {
            v2f a = (v2f){hb, hb};
            #pragma unroll
            for (int c = 0; c < 8; ++c) a += vvp[c][p] * wr[c];
            v2f g = gelu2(a);
            #pragma unroll
            for (int c6 = 0; c6 < 6; ++c6) so2[c6][p] += g * w2r[c6];
        }
    }
    const float nuv = nu[0];
    #pragma unroll
    for (int c6 = 0; c6 < 6; ++c6) {
        v2f r0 = 0.3f * so2[c6][0];
        v2f r1 = 0.3f * so2[c6][1];
        if (c6 < 3) {
            const v2f* up = (const v2f*)&uv[c6];
            r0 += up[0] * nuv;
            r1 += up[1] * nuv;
        }
        *(float4*)&out[(size_t)(b * 6 + c6) * 262144 + sp] =
            make_float4(r0.x, r0.y, r1.x, r1.y);
    }
}

// pack split re/im spectral leaves into interleaved float2, ALL 16 weights
// in one dispatch (pointers passed by value).
struct PackPtrs { const float* re[16]; const float* im[16]; };

__global__ __launch_bounds__(256) void k_pack_all(PackPtrs p, float2* __restrict__ dst)
{
    int i = blockIdx.x * 256 + threadIdx.x;   // 65536 = 16 * 4096
    int w = i >> 12, idx = i & 4095;
    dst[i] = make_float2(p.re[w][idx], p.im[w][idx]);
}

// ---------------------------------------------------------------------------
extern "C" void kernel_launch(void* const* d_in, const int* in_sizes, int n_in,
                              void* d_out, int out_size, void* d_ws, size_t ws_size,
                              hipStream_t stream)
{
    (void)out_size;
    const char* leaf[32];
    bool spec_split = false;
    const char* spec_re[16]; const char* spec_im[16];
    int src = 0;
    leaf[0] = (const char*)d_in[src++];
    leaf[1] = (const char*)d_in[src++];
    leaf[2] = (const char*)d_in[src++];
    leaf[3] = (const char*)d_in[src++];
    {
        int s = (src < n_in) ? in_sizes[src] : 4096;
        if (n_in >= 48 && s == 4096) {
            spec_split = true;
            for (int i = 0; i < 16; ++i) {
                spec_re[i] = (const char*)d_in[src++];
                spec_im[i] = (const char*)d_in[src++];
            }
        } else {
            int per;
            if (s == 4096 || s == 8192) per = 1;
            else if (s == 16384 || s == 32768) per = 4;
            else per = 16;
            for (int i = 0; i < 16; i += per) {
                const char* base = (const char*)d_in[src++];
                for (int j = 0; j < per; ++j) leaf[4 + i + j] = base + (size_t)j * 4096 * 8;
            }
        }
    }
    {
        int s = (src < n_in) ? in_sizes[src] : 64;
        if (s == 64) { for (int i = 0; i < 4; ++i) leaf[20 + i] = (const char*)d_in[src++]; }
        else { const char* base = (const char*)d_in[src++];
               for (int i = 0; i < 4; ++i) leaf[20 + i] = base + (size_t)i * 64 * 4; }
    }
    {
        int s = (src < n_in) ? in_sizes[src] : 8;
        if (s == 8) { for (int i = 0; i < 4; ++i) leaf[24 + i] = (const char*)d_in[src++]; }
        else { const char* base = (const char*)d_in[src++];
               for (int i = 0; i < 4; ++i) leaf[24 + i] = base + (size_t)i * 8 * 4; }
    }
    leaf[28] = (const char*)d_in[src++];
    leaf[29] = (const char*)d_in[src++];
    leaf[30] = (const char*)d_in[src++];
    leaf[31] = (const char*)d_in[src++];

    const float* u    = (const float*)leaf[0];
    const float* nu   = (const float*)leaf[1];
    const float* fc0w = (const float*)leaf[2];
    const float* fc0b = (const float*)leaf[3];
    const float* convw[4], *convb[4];
    for (int i = 0; i < 4; ++i) { convw[i] = (const float*)leaf[20 + i];
                                  convb[i] = (const float*)leaf[24 + i]; }
    const float* fc1w = (const float*)leaf[28];
    const float* fc1b = (const float*)leaf[29];
    const float* fc2w = (const float*)leaf[30];
    const float* fc2b = (const float*)leaf[31];

    // scratch: x | A | Bh | O | SP.  Fallback: A,Bh,SP in d_out (dead before
    // k_ptout writes it); O must stay in ws (live during k_ptout).
    const size_t szX = 67108864, szA = 8388608, szB = 1048576,
                 szO = 131072, szSP = 524288;
    char* ws = (char*)d_ws;
    float* xbuf = (float*)ws;
    float2 *Abuf, *Bbuf, *Obuf, *SP;
    if (ws_size >= szX + szA + szB + szO + szSP) {
        Abuf = (float2*)(ws + szX);
        Bbuf = (float2*)(ws + szX + szA);
        Obuf = (float2*)(ws + szX + szA + szB);
        SP   = (float2*)(ws + szX + szA + szB + szO);
    } else {
        Obuf = (float2*)(ws + szX);
        Abuf = (float2*)d_out;
        Bbuf = (float2*)((char*)d_out + szA);
        SP   = (float2*)((char*)d_out + szA + szB);
    }

    const float2* specw[16];
    if (spec_split) {
        PackPtrs pp;
        for (int i = 0; i < 16; ++i) {
            pp.re[i] = (const float*)spec_re[i];
            pp.im[i] = (const float*)spec_im[i];
            specw[i] = SP + (size_t)i * 4096;
        }
        hipLaunchKernelGGL(k_pack_all, dim3(256), dim3(256), 0, stream, pp, SP);
    } else {
        for (int i = 0; i < 16; ++i) specw[i] = (const float2*)leaf[4 + i];
    }
    float* outp = (float*)d_out;

    hipLaunchKernelGGL(k_liftA, dim3(2048), dim3(256), 0, stream, u, fc0w, fc0b, xbuf, Abuf);
    for (int L = 0; L < 4; ++L) {
        hipLaunchKernelGGL(k_fH, dim3(256), dim3(256), 0, stream, Abuf, Bbuf);
        hipLaunchKernelGGL(k_fDmix, dim3(64), dim3(256), 0, stream,
                           Bbuf, specw[L*4+0], specw[L*4+1], specw[L*4+2], specw[L*4+3], Obuf);
        if (L < 3) {
            hipLaunchKernelGGL(k_ptA, dim3(2048), dim3(256), 0, stream,
                               xbuf, Obuf, convw[L], convb[L], Abuf);
        } else {
            hipLaunchKernelGGL(k_ptout, dim3(2048), dim3(256), 0, stream,
                               xbuf, Obuf, convw[3], convb[3], u, nu,
                               fc1w, fc1b, fc2w, fc2b, outp);
        }
    }
}

// Round 7
// 279.757 us; speedup vs baseline: 1.0304x; 1.0304x over previous
//
#include <hip/hip_runtime.h>

// FNO3d forward, MI355X. Round 13 (base = R11, 282.5us):
//  - k_fH v2: kz-paired + dy-split-2 across adjacent lanes. Keeps 131072
//    threads (512x256, 2 waves/SIMD -- R12's grid-256 version halved
//    parallelism and regressed). 32 float4 loads/thread (half the load
//    count, fully coalesced: lane quads cover 64B contiguous), DPP
//    quad_perm pair-combine, even lane writes float4.
//  - k_ptout fc loop unroll 4 -> 8 (s_load batching, SGPR-only cost).
//  - Everything else exactly R11.
//
// Layouts:
//   x  : float [B=8][C=8][64][64][64]          (67,108,864 B)
//   A  : float2[8][8][dx=64][dy=64][kz=4]      ( 8,388,608 B)
//   Bh : float2[8][8][dx=64][ky=8][kz=4]       ( 1,048,576 B)
//   O  : float2[8][8][kx=8][ky=8][kz=4]        (   131,072 B)

#define TWO_PI_OVER_64 0.09817477042468103

typedef float v2f __attribute__((ext_vector_type(2)));

__device__ __forceinline__ float gelu_fast(float x) {
    float x2 = x * x;
    float p  = x * (1.0f + 0.044715f * x2);
    float e  = __builtin_amdgcn_exp2f(-2.3022083f * p);
    return x * __builtin_amdgcn_rcpf(1.0f + e);
}

__device__ __forceinline__ v2f gelu2(v2f x) {
    v2f x2 = x * x;
    v2f p  = x * (1.0f + 0.044715f * x2);
    v2f r;
    r.x = __builtin_amdgcn_rcpf(1.0f + __builtin_amdgcn_exp2f(-2.3022083f * p.x));
    r.y = __builtin_amdgcn_rcpf(1.0f + __builtin_amdgcn_exp2f(-2.3022083f * p.y));
    return x * r;
}

#define BUILD_TW() \
    __shared__ float twc[64], tws[64]; \
    if (threadIdx.x < 64) { \
        double a_ = TWO_PI_OVER_64 * (double)threadIdx.x; \
        twc[threadIdx.x] = (float)cos(a_); tws[threadIdx.x] = (float)sin(a_); \
    }

// Twiddle pair registers for the W-axis (w = wq*4 + {0..3}), packed by j-pair.
#define LOAD_WTW() \
    v2f c1p[2], s1p[2], c2p[2], s2p[2], c3p[2], s3p[2]; \
    _Pragma("unroll") \
    for (int p = 0; p < 2; ++p) { \
        int wa = wq * 4 + 2 * p, wb = wa + 1; \
        c1p[p] = (v2f){twc[wa], twc[wb]}; \
        s1p[p] = (v2f){tws[wa], tws[wb]}; \
        c2p[p] = (v2f){twc[(2 * wa) & 63], twc[(2 * wb) & 63]}; \
        s2p[p] = (v2f){tws[(2 * wa) & 63], tws[(2 * wb) & 63]}; \
        c3p[p] = (v2f){twc[(3 * wa) & 63], twc[(3 * wb) & 63]}; \
        s3p[p] = (v2f){tws[(3 * wa) & 63], tws[(3 * wb) & 63]}; \
    }

// DPP row_ror rotation-add: after steps 1,2,4,8 every lane of each 16-lane
// row holds the row sum. VALU-only (no ds_bpermute / LDS pipe).
#define ROR_STEP(x, CTRL) \
    x += __int_as_float(__builtin_amdgcn_update_dpp( \
            0, __float_as_int(x), CTRL, 0xF, 0xF, true))

__device__ __forceinline__ float red16_ror(float x) {
    ROR_STEP(x, 0x121);   // row_ror:1
    ROR_STEP(x, 0x122);   // row_ror:2
    ROR_STEP(x, 0x124);   // row_ror:4
    ROR_STEP(x, 0x128);   // row_ror:8
    return x;
}

// adjacent-lane pair add: quad_perm [1,0,3,2]
__device__ __forceinline__ float addswap1(float x) {
    return x + __int_as_float(__builtin_amdgcn_update_dpp(
            0, __float_as_int(x), 0xB1, 0xF, 0xF, true));
}

// A-tail: partial W-DFT over this lane's 4 w-points (as 2 packed pairs),
// DPP reduce across the 16 wq-lanes, predicated float4 store.
__device__ __forceinline__ void a_tail_store(
    const v2f v[2], const v2f c1[2], const v2f s1[2],
    const v2f c2[2], const v2f s2[2], const v2f c3[2], const v2f s3[2],
    int wq, float2* __restrict__ Arow)
{
    v2f d;
    d = v[0] + v[1];               float p0  = d.x + d.y;
    d = v[0]*c1[0] + v[1]*c1[1];   float ar1 = d.x + d.y;
    d = v[0]*s1[0] + v[1]*s1[1];   float ai1 = -(d.x + d.y);
    d = v[0]*c2[0] + v[1]*c2[1];   float ar2 = d.x + d.y;
    d = v[0]*s2[0] + v[1]*s2[1];   float ai2 = -(d.x + d.y);
    d = v[0]*c3[0] + v[1]*c3[1];   float ar3 = d.x + d.y;
    d = v[0]*s3[0] + v[1]*s3[1];   float ai3 = -(d.x + d.y);
    p0  = red16_ror(p0);
    ar1 = red16_ror(ar1);  ai1 = red16_ror(ai1);
    ar2 = red16_ror(ar2);  ai2 = red16_ror(ai2);
    ar3 = red16_ror(ar3);  ai3 = red16_ror(ai3);
    if (wq < 2) {
        float4 av;
        av.x = (wq == 0) ? p0   : ar2;
        av.y = (wq == 0) ? 0.f  : ai2;
        av.z = (wq == 0) ? ar1  : ar3;
        av.w = (wq == 0) ? ai1  : ai3;
        *((float4*)Arow + wq) = av;
    }
}

// ---------------------------------------------------------------------------
// Lift (3->8 ch) + forward W-DFT (DPP tail), packed fp32.
// grid 2048 = b(8)*dx(64)*dyq(4); block 256 (dyl = t>>4, wq = t&15).
// ---------------------------------------------------------------------------
__global__ __launch_bounds__(256) void k_liftA(
    const float* __restrict__ u, const float* __restrict__ fc0w,
    const float* __restrict__ fc0b, float* __restrict__ x,
    float2* __restrict__ A)
{
    BUILD_TW();
    const int t = threadIdx.x, bid = blockIdx.x;
    const int b = bid >> 8, dx = (bid >> 2) & 63, dy0 = (bid & 3) * 16;
    const int dyl = t >> 4, wq = t & 15;
    const size_t sp = (size_t)dx * 4096 + (size_t)(dy0 + dyl) * 64 + wq * 4;
    v2f uin[3][2];
    #pragma unroll
    for (int c = 0; c < 3; ++c) {
        float4 v = *(const float4*)&u[(size_t)(b * 3 + c) * 262144 + sp];
        uin[c][0] = (v2f){v.x, v.y};
        uin[c][1] = (v2f){v.z, v.w};
    }
    __syncthreads();
    LOAD_WTW();
    #pragma unroll
    for (int o = 0; o < 8; ++o) {
        float w0 = fc0w[o * 3 + 0], w1 = fc0w[o * 3 + 1], w2 = fc0w[o * 3 + 2];
        float bb = fc0b[o];
        v2f vp[2];
        #pragma unroll
        for (int p = 0; p < 2; ++p)
            vp[p] = bb + uin[0][p] * w0 + uin[1][p] * w1 + uin[2][p] * w2;
        *(float4*)&x[(size_t)(b * 8 + o) * 262144 + sp] =
            make_float4(vp[0].x, vp[0].y, vp[1].x, vp[1].y);
        a_tail_store(vp, c1p, s1p, c2p, s2p, c3p, s3p, wq,
                     A + ((size_t)(b * 8 + o) * 4096 + dx * 64 + dy0 + dyl) * 4);
    }
}

// ---------------------------------------------------------------------------
// H-axis DFT v2: A[b,c,dx,dy,kz] -> Bh[b,c,dx,ky,kz]. grid 512, block 256.
// Thread g: pid = g>>1 (output float4 = kz pair), half = g&1 sums dy = half,
// half+2, ... (32 float4 loads, coalesced 64B per lane-quad). DPP pair-add
// combines halves; even lane stores float4.
// ---------------------------------------------------------------------------
__global__ __launch_bounds__(256) void k_fH(const float2* __restrict__ A,
                                            float2* __restrict__ Bh)
{
    BUILD_TW();
    __syncthreads();
    const int g = blockIdx.x * 256 + threadIdx.x;   // 131072
    const int pid = g >> 1, half = g & 1;
    const int kz2 = (pid & 1) * 2;
    const int ky  = (pid >> 1) & 7;
    const int dx  = (pid >> 4) & 63;
    const int c   = (pid >> 10) & 7;
    const int b   = pid >> 13;
    const int kyv = ky < 4 ? ky : ky + 56;
    const float2* Ap = A + (size_t)(b * 8 + c) * 16384 + dx * 256 + half * 4 + kz2;
    float re0 = 0.f, im0 = 0.f, re1 = 0.f, im1 = 0.f;
    int ti = (kyv * half) & 63;
    const int step = (kyv * 2) & 63;
    #pragma unroll 8
    for (int i = 0; i < 32; ++i) {
        float4 a = *(const float4*)&Ap[i * 8];   // dy = half + 2i
        float cc = twc[ti], ss = tws[ti];
        re0 += a.x * cc + a.y * ss;   // * e^{-i phi}
        im0 += a.y * cc - a.x * ss;
        re1 += a.z * cc + a.w * ss;
        im1 += a.w * cc - a.z * ss;
        ti = (ti + step) & 63;
    }
    re0 = addswap1(re0);  im0 = addswap1(im0);
    re1 = addswap1(re1);  im1 = addswap1(im1);
    if (half == 0)
        *(float4*)&Bh[(size_t)(b * 8 + c) * 2048 + dx * 32 + ky * 4 + kz2] =
            make_float4(re0, im0, re1, im1);
}

// ---------------------------------------------------------------------------
// D-axis DFT (into LDS) + spectral mix. grid 64, block 256. (R7)
// ---------------------------------------------------------------------------
__global__ __launch_bounds__(256) void k_fDmix(
    const float2* __restrict__ Bh,
    const float2* __restrict__ w1, const float2* __restrict__ w2,
    const float2* __restrict__ w3, const float2* __restrict__ w4,
    float2* __restrict__ O)
{
    BUILD_TW();
    __shared__ float2 Cs[256];   // [c][ky][kz] = c*32 + ky*4 + kz
    const int t = threadIdx.x, bid = blockIdx.x;
    const int b = bid >> 3, kx = bid & 7;
    const int kxv = kx < 4 ? kx : kx + 56;
    __syncthreads();
    {
        int kz = t & 3, ky = (t >> 2) & 7, c = t >> 5;
        const float2* Bp = Bh + (size_t)(b * 8 + c) * 2048 + ky * 4 + kz;
        float re = 0.f, im = 0.f;
        int ti = 0;
        #pragma unroll 8
        for (int dx = 0; dx < 64; ++dx) {
            float2 v = Bp[dx * 32];
            float cc = twc[ti], ss = tws[ti];
            re += v.x * cc + v.y * ss;
            im += v.y * cc - v.x * ss;
            ti = (ti + kxv) & 63;
        }
        Cs[t] = make_float2(re, im);
    }
    __syncthreads();
    {
        int kz = t & 3, ky = (t >> 2) & 7, o = t >> 5;
        const float2* wsel = (kx < 4) ? ((ky < 4) ? w1 : w3) : ((ky < 4) ? w2 : w4);
        int kxw = kx & 3, kyw = ky & 3;
        float re = 0.f, im = 0.f;
        #pragma unroll
        for (int i = 0; i < 8; ++i) {
            float2 cv = Cs[i * 32 + ky * 4 + kz];
            float2 wv = wsel[(((size_t)(i * 8 + o) * 4 + kxw) * 4 + kyw) * 4 + kz];
            re += cv.x * wv.x - cv.y * wv.y;
            im += cv.x * wv.y + cv.y * wv.x;
        }
        O[(((size_t)(b * 8 + o) * 8 + kx) * 8 + ky) * 4 + kz] = make_float2(re, im);
    }
}

// ---------------------------------------------------------------------------
// Inverse D/H DFT in LDS + irfftW + conv + gelu + x in place + next-layer A.
// Packed fp32 over the j-pairs. grid 2048; block 256. (R11)
// ---------------------------------------------------------------------------
__global__ __launch_bounds__(256, 4) void k_ptA(
    float* __restrict__ x, const float2* __restrict__ O,
    const float* __restrict__ cw, const float* __restrict__ cb,
    float2* __restrict__ A)
{
    BUILD_TW();
    __shared__ float2 Ps[256];          // [o][ky][kz]
    __shared__ float2 Qs[8 * 16 * 4];   // [o][dyl][kz]
    const int t = threadIdx.x, bid = blockIdx.x;
    const int b = bid >> 8, dx = (bid >> 2) & 63, dy0 = (bid & 3) * 16;
    const int dyl = t >> 4, wq = t & 15;
    const size_t sp = (size_t)dx * 4096 + (size_t)(dy0 + dyl) * 64 + wq * 4;
    // ---- prefetch: all global loads issued before any barrier ----
    float4 xv[8];
    #pragma unroll
    for (int c = 0; c < 8; ++c)
        xv[c] = *(const float4*)&x[(size_t)(b * 8 + c) * 262144 + sp];
    const int pkz = t & 3, pky = (t >> 2) & 7, po = t >> 5;
    float2 ov[8];
    #pragma unroll
    for (int kxi = 0; kxi < 8; ++kxi)
        ov[kxi] = O[(((size_t)(b * 8 + po) * 8 + kxi) * 8 + pky) * 4 + pkz];
    __syncthreads();
    {   // Ps
        float re = 0.f, im = 0.f;
        #pragma unroll
        for (int kxi = 0; kxi < 8; ++kxi) {
            int kxv = kxi < 4 ? kxi : kxi + 56;
            int ti = (kxv * dx) & 63;
            float cc = twc[ti], ss = tws[ti];
            re += ov[kxi].x * cc - ov[kxi].y * ss;   // * e^{+i phi}
            im += ov[kxi].y * cc + ov[kxi].x * ss;
        }
        Ps[t] = make_float2(re, im);
    }
    __syncthreads();
    for (int it = t; it < 512; it += 256) {  // Qs
        int kz = it & 3, qdyl = (it >> 2) & 15, o = it >> 6;
        int dy = dy0 + qdyl;
        float re = 0.f, im = 0.f;
        #pragma unroll
        for (int kyi = 0; kyi < 8; ++kyi) {
            int kyv = kyi < 4 ? kyi : kyi + 56;
            int ti = (kyv * dy) & 63;
            float2 v = Ps[(o * 8 + kyi) * 4 + kz];
            float cc = twc[ti], ss = tws[ti];
            re += v.x * cc - v.y * ss;
            im += v.y * cc + v.x * ss;
        }
        Qs[(o * 16 + qdyl) * 4 + kz] = make_float2(re, im);
    }
    __syncthreads();
    LOAD_WTW();
    const float invN3 = 1.0f / 262144.0f;
    #pragma unroll
    for (int o = 0; o < 8; ++o) {
        float4 qa = *(const float4*)&Qs[(o * 16 + dyl) * 4];      // q0,q1
        float4 qb = *(const float4*)&Qs[(o * 16 + dyl) * 4 + 2];  // q2,q3
        const float cbo = cb[o];
        v2f outp[2];
        #pragma unroll
        for (int p = 0; p < 2; ++p) {
            v2f x1 = qa.x + 2.f * (qa.z * c1p[p] - qa.w * s1p[p]
                                 + qb.x * c2p[p] - qb.y * s2p[p]
                                 + qb.z * c3p[p] - qb.w * s3p[p]);
            x1 *= invN3;
            v2f x2 = (v2f){cbo, cbo};
            #pragma unroll
            for (int c = 0; c < 8; ++c) {
                const v2f* xp = (const v2f*)&xv[c];
                x2 += cw[o * 8 + c] * xp[p];
            }
            outp[p] = gelu2(x1 + x2);
        }
        *(float4*)&x[(size_t)(b * 8 + o) * 262144 + sp] =
            make_float4(outp[0].x, outp[0].y, outp[1].x, outp[1].y);
        a_tail_store(outp, c1p, s1p, c2p, s2p, c3p, s3p, wq,
                     A + ((size_t)(b * 8 + o) * 4096 + dx * 64 + dy0 + dyl) * 4);
    }
}

// ---------------------------------------------------------------------------
// Layer 3: inverse DFT + conv (no gelu) -> fc1+gelu+fc2, + hard core u*nu.
// Packed fp32 over the j-pairs. Writes d_out only. grid 2048; block 256.
// ---------------------------------------------------------------------------
__global__ __launch_bounds__(256, 4) void k_ptout(
    const float* __restrict__ x, const float2* __restrict__ O,
    const float* __restrict__ cw, const float* __restrict__ cb,
    const float* __restrict__ u, const float* __restrict__ nu,
    const float* __restrict__ fc1w, const float* __restrict__ fc1b,
    const float* __restrict__ fc2w, const float* __restrict__ fc2b,
    float* __restrict__ out)
{
    BUILD_TW();
    __shared__ float2 Ps[256];
    __shared__ float2 Qs[8 * 16 * 4];
    const int t = threadIdx.x, bid = blockIdx.x;
    const int b = bid >> 8, dx = (bid >> 2) & 63, dy0 = (bid & 3) * 16;
    const int dyl = t >> 4, wq = t & 15;
    const size_t sp = (size_t)dx * 4096 + (size_t)(dy0 + dyl) * 64 + wq * 4;
    float4 xv[8];
    #pragma unroll
    for (int c = 0; c < 8; ++c)
        xv[c] = *(const float4*)&x[(size_t)(b * 8 + c) * 262144 + sp];
    float4 uv[3];
    #pragma unroll
    for (int c = 0; c < 3; ++c)
        uv[c] = *(const float4*)&u[(size_t)(b * 3 + c) * 262144 + sp];
    const int pkz = t & 3, pky = (t >> 2) & 7, po = t >> 5;
    float2 ovv[8];
    #pragma unroll
    for (int kxi = 0; kxi < 8; ++kxi)
        ovv[kxi] = O[(((size_t)(b * 8 + po) * 8 + kxi) * 8 + pky) * 4 + pkz];
    __syncthreads();
    {
        float re = 0.f, im = 0.f;
        #pragma unroll
        for (int kxi = 0; kxi < 8; ++kxi) {
            int kxv = kxi < 4 ? kxi : kxi + 56;
            int ti = (kxv * dx) & 63;
            float cc = twc[ti], ss = tws[ti];
            re += ovv[kxi].x * cc - ovv[kxi].y * ss;
            im += ovv[kxi].y * cc + ovv[kxi].x * ss;
        }
        Ps[t] = make_float2(re, im);
    }
    __syncthreads();
    for (int it = t; it < 512; it += 256) {
        int kz = it & 3, qdyl = (it >> 2) & 15, o = it >> 6;
        int dy = dy0 + qdyl;
        float re = 0.f, im = 0.f;
        #pragma unroll
        for (int kyi = 0; kyi < 8; ++kyi) {
            int kyv = kyi < 4 ? kyi : kyi + 56;
            int ti = (kyv * dy) & 63;
            float2 v = Ps[(o * 8 + kyi) * 4 + kz];
            float cc = twc[ti], ss = tws[ti];
            re += v.x * cc - v.y * ss;
            im += v.y * cc + v.x * ss;
        }
        Qs[(o * 16 + qdyl) * 4 + kz] = make_float2(re, im);
    }
    __syncthreads();
    LOAD_WTW();
    const float invN3 = 1.0f / 262144.0f;
    v2f vvp[8][2];   // layer-3 activations (no gelu), packed j-pairs
    #pragma unroll
    for (int o = 0; o < 8; ++o) {
        float4 qa = *(const float4*)&Qs[(o * 16 + dyl) * 4];
        float4 qb = *(const float4*)&Qs[(o * 16 + dyl) * 4 + 2];
        const float cbo = cb[o];
        #pragma unroll
        for (int p = 0; p < 2; ++p) {
            v2f x1 = qa.x + 2.f * (qa.z * c1p[p] - qa.w * s1p[p]
                                 + qb.x * c2p[p] - qb.y * s2p[p]
                                 + qb.z * c3p[p] - qb.w * s3p[p]);
            x1 *= invN3;
            v2f x2 = (v2f){cbo, cbo};
            #pragma unroll
            for (int c = 0; c < 8; ++c) {
                const v2f* xp = (const v2f*)&xv[c];
                x2 += cw[o * 8 + c] * xp[p];
            }
            vvp[o][p] = x1 + x2;
        }
    }
    v2f so2[6][2];
    #pragma unroll
    for (int c6 = 0; c6 < 6; ++c6) {
        float bb = fc2b[c6];
        so2[c6][0] = (v2f){bb, bb};
        so2[c6][1] = (v2f){bb, bb};
    }
    #pragma unroll 8
    for (int h = 0; h < 32; ++h) {
        float wr[8];
        #pragma unroll
        for (int c = 0; c < 8; ++c) wr[c] = fc1w[h * 8 + c];   // uniform -> SGPR
        const float hb = fc1b[h];
        float w2r[6];
        #pragma unroll
        for (int c6 = 0; c6 < 6; ++c6) w2r[c6] = fc2w[c6 * 32 + h];
        #pragma unroll
        for (int p = 0; p < 2; ++p) {
            v2f a = (v2f){hb, hb};
            #pragma unroll
            for (int c = 0; c < 8; ++c) a += vvp[c][p] * wr[c];
            v2f g = gelu2(a);
            #pragma unroll
            for (int c6 = 0; c6 < 6; ++c6) so2[c6][p] += g * w2r[c6];
        }
    }
    const float nuv = nu[0];
    #pragma unroll
    for (int c6 = 0; c6 < 6; ++c6) {
        v2f r0 = 0.3f * so2[c6][0];
        v2f r1 = 0.3f * so2[c6][1];
        if (c6 < 3) {
            const v2f* up = (const v2f*)&uv[c6];
            r0 += up[0] * nuv;
            r1 += up[1] * nuv;
        }
        *(float4*)&out[(size_t)(b * 6 + c6) * 262144 + sp] =
            make_float4(r0.x, r0.y, r1.x, r1.y);
    }
}

// pack split re/im spectral leaves into interleaved float2, ALL 16 weights
// in one dispatch (pointers passed by value).
struct PackPtrs { const float* re[16]; const float* im[16]; };

__global__ __launch_bounds__(256) void k_pack_all(PackPtrs p, float2* __restrict__ dst)
{
    int i = blockIdx.x * 256 + threadIdx.x;   // 65536 = 16 * 4096
    int w = i >> 12, idx = i & 4095;
    dst[i] = make_float2(p.re[w][idx], p.im[w][idx]);
}

// ---------------------------------------------------------------------------
extern "C" void kernel_launch(void* const* d_in, const int* in_sizes, int n_in,
                              void* d_out, int out_size, void* d_ws, size_t ws_size,
                              hipStream_t stream)
{
    (void)out_size;
    const char* leaf[32];
    bool spec_split = false;
    const char* spec_re[16]; const char* spec_im[16];
    int src = 0;
    leaf[0] = (const char*)d_in[src++];
    leaf[1] = (const char*)d_in[src++];
    leaf[2] = (const char*)d_in[src++];
    leaf[3] = (const char*)d_in[src++];
    {
        int s = (src < n_in) ? in_sizes[src] : 4096;
        if (n_in >= 48 && s == 4096) {
            spec_split = true;
            for (int i = 0; i < 16; ++i) {
                spec_re[i] = (const char*)d_in[src++];
                spec_im[i] = (const char*)d_in[src++];
            }
        } else {
            int per;
            if (s == 4096 || s == 8192) per = 1;
            else if (s == 16384 || s == 32768) per = 4;
            else per = 16;
            for (int i = 0; i < 16; i += per) {
                const char* base = (const char*)d_in[src++];
                for (int j = 0; j < per; ++j) leaf[4 + i + j] = base + (size_t)j * 4096 * 8;
            }
        }
    }
    {
        int s = (src < n_in) ? in_sizes[src] : 64;
        if (s == 64) { for (int i = 0; i < 4; ++i) leaf[20 + i] = (const char*)d_in[src++]; }
        else { const char* base = (const char*)d_in[src++];
               for (int i = 0; i < 4; ++i) leaf[20 + i] = base + (size_t)i * 64 * 4; }
    }
    {
        int s = (src < n_in) ? in_sizes[src] : 8;
        if (s == 8) { for (int i = 0; i < 4; ++i) leaf[24 + i] = (const char*)d_in[src++]; }
        else { const char* base = (const char*)d_in[src++];
               for (int i = 0; i < 4; ++i) leaf[24 + i] = base + (size_t)i * 8 * 4; }
    }
    leaf[28] = (const char*)d_in[src++];
    leaf[29] = (const char*)d_in[src++];
    leaf[30] = (const char*)d_in[src++];
    leaf[31] = (const char*)d_in[src++];

    const float* u    = (const float*)leaf[0];
    const float* nu   = (const float*)leaf[1];
    const float* fc0w = (const float*)leaf[2];
    const float* fc0b = (const float*)leaf[3];
    const float* convw[4], *convb[4];
    for (int i = 0; i < 4; ++i) { convw[i] = (const float*)leaf[20 + i];
                                  convb[i] = (const float*)leaf[24 + i]; }
    const float* fc1w = (const float*)leaf[28];
    const float* fc1b = (const float*)leaf[29];
    const float* fc2w = (const float*)leaf[30];
    const float* fc2b = (const float*)leaf[31];

    // scratch: x | A | Bh | O | SP.  Fallback: A,Bh,SP in d_out (dead before
    // k_ptout writes it); O must stay in ws (live during k_ptout).
    const size_t szX = 67108864, szA = 8388608, szB = 1048576,
                 szO = 131072, szSP = 524288;
    char* ws = (char*)d_ws;
    float* xbuf = (float*)ws;
    float2 *Abuf, *Bbuf, *Obuf, *SP;
    if (ws_size >= szX + szA + szB + szO + szSP) {
        Abuf = (float2*)(ws + szX);
        Bbuf = (float2*)(ws + szX + szA);
        Obuf = (float2*)(ws + szX + szA + szB);
        SP   = (float2*)(ws + szX + szA + szB + szO);
    } else {
        Obuf = (float2*)(ws + szX);
        Abuf = (float2*)d_out;
        Bbuf = (float2*)((char*)d_out + szA);
        SP   = (float2*)((char*)d_out + szA + szB);
    }

    const float2* specw[16];
    if (spec_split) {
        PackPtrs pp;
        for (int i = 0; i < 16; ++i) {
            pp.re[i] = (const float*)spec_re[i];
            pp.im[i] = (const float*)spec_im[i];
            specw[i] = SP + (size_t)i * 4096;
        }
        hipLaunchKernelGGL(k_pack_all, dim3(256), dim3(256), 0, stream, pp, SP);
    } else {
        for (int i = 0; i < 16; ++i) specw[i] = (const float2*)leaf[4 + i];
    }
    float* outp = (float*)d_out;

    hipLaunchKernelGGL(k_liftA, dim3(2048), dim3(256), 0, stream, u, fc0w, fc0b, xbuf, Abuf);
    for (int L = 0; L < 4; ++L) {
        hipLaunchKernelGGL(k_fH, dim3(512), dim3(256), 0, stream, Abuf, Bbuf);
        hipLaunchKernelGGL(k_fDmix, dim3(64), dim3(256), 0, stream,
                           Bbuf, specw[L*4+0], specw[L*4+1], specw[L*4+2], specw[L*4+3], Obuf);
        if (L < 3) {
            hipLaunchKernelGGL(k_ptA, dim3(2048), dim3(256), 0, stream,
                               xbuf, Obuf, convw[L], convb[L], Abuf);
        } else {
            hipLaunchKernelGGL(k_ptout, dim3(2048), dim3(256), 0, stream,
                               xbuf, Obuf, convw[3], convb[3], u, nu,
                               fc1w, fc1b, fc2w, fc2b, outp);
        }
    }
}